// Round 6
// baseline (340.154 us; speedup 1.0000x reference)
//
#include <hip/hip_runtime.h>
#include <hip/hip_bf16.h>

constexpr int BATCH = 4;
constexpr int H = 96, W = 96, HW = H * W;
constexpr int NBR = 3;

using bf16x8 = __attribute__((ext_vector_type(8))) short;  // 8 bf16 in 4 VGPRs
using f32x4 = __attribute__((ext_vector_type(4))) float;

static __device__ __forceinline__ float leakyf(float x) {
    return x >= 0.f ? x : 0.1f * x;
}

static __device__ __forceinline__ short f2bf(float x) {
    __hip_bfloat16 h = __float2bfloat16(x);
    return *reinterpret_cast<short*>(&h);
}

static __device__ __forceinline__ float bf2f(short s) {
    __hip_bfloat16 h = *reinterpret_cast<__hip_bfloat16*>(&s);
    return __bfloat162float(h);
}

// ---- fused: ref NCHW fp32 -> REFT (bf16 ch-last) + NRT (normalized fp32) ---
__global__ __launch_bounds__(256) void k_pre(const float* __restrict__ ref,
                                             short* __restrict__ reft,
                                             float* __restrict__ nrt) {
    int p = blockIdx.x * 256 + threadIdx.x;
    if (p >= BATCH * HW) return;
    int b = p / HW, ij = p % HW;
    const float* src = ref + b * 64 * HW + ij;
    float v[64];
    float ss = 0.f;
#pragma unroll
    for (int c = 0; c < 64; ++c) {
        v[c] = src[c * HW];
        ss += v[c] * v[c];
    }
    float inv = 1.f / fmaxf(sqrtf(ss), 1e-12f);
    short* rd = reft + (size_t)p * 64;
#pragma unroll
    for (int cc = 0; cc < 8; ++cc) {
        bf16x8 o;
#pragma unroll
        for (int j = 0; j < 8; ++j) o[j] = f2bf(v[cc * 8 + j]);
        *(bf16x8*)(rd + cc * 8) = o;
    }
    float* nd = nrt + (size_t)p * 64;
#pragma unroll
    for (int c = 0; c < 64; ++c) nd[c] = v[c] * inv;
}

// ---- pack conv weights (OIHW fp32) into MFMA-B fragment layout -------------
// dst[tap][kk][nt][lane][e]; ic = kk*32+(l>>4)*8+e, oc = nt*16+(l&15)
__global__ void k_prep(const float* __restrict__ src, short* __restrict__ dst,
                       int OC, int ICt, int ICsrc, int KH, int KW, int NT,
                       int fold, int total) {
    int i = blockIdx.x * 256 + threadIdx.x;
    if (i >= total) return;
    int e = i & 7, l = (i >> 3) & 63;
    int rest = i >> 9;
    int nt = rest % NT;
    rest /= NT;
    int ICK = ICt >> 5;
    int kk = rest % ICK;
    int tap = rest / ICK;
    int ic = kk * 32 + (l >> 4) * 8 + e;
    int oc = nt * 16 + (l & 15);
    int u = tap / KW, v = tap % KW;
    float val = 0.f;
    if (oc < OC) {
        val = src[((oc * ICsrc + ic) * KH + u) * KW + v];
        if (fold) val += src[((oc * ICsrc + 64 + ic) * KH + u) * KW + v];
    }
    dst[i] = f2bf(val);
}

// ---- channel-last bf16 implicit-GEMM conv ----------------------------------
// tile 8x32 px, 8 waves x (2 Mtiles x NTb Ntiles). X staged in LDS (XOR swz),
// B staged in LDS when BLDS, else streamed. NSPL: split OC across blocks.
// OMODE 0: bf16 ch-last + leaky; 1: bf16 ch-last 72 (no act); 2: NCHW fp32 + leaky
template <int KH, int KW, int IC, int OC, int OMODE, bool BLDS, int NSPL>
__global__ __launch_bounds__(512) void k_cmfma(
    const short* __restrict__ inA, const short* __restrict__ inB,
    const short* __restrict__ Bp, const float* __restrict__ bias,
    void* __restrict__ outp) {
    constexpr int TI = 8, TJ = 32;
    constexpr int PH = (KH - 1) / 2, PW = (KW - 1) / 2;
    constexpr int LR = TI + KH - 1, LC = TJ + KW - 1;
    constexpr int ICB = IC * 2;
    constexpr int LS = (ICB == 128) ? 7 : 8;
    constexpr int ICK = IC / 32;
    constexpr int NTF = (OC + 15) / 16;
    constexpr int NTb = NTF / NSPL;
    constexpr int TAPS = KH * KW;
    constexpr int NOCT = ICB / 16;
    __shared__ char Xs[LR * LC * ICB];
    __shared__ short Bs[BLDS ? TAPS * ICK * NTb * 512 : 8];
    const int tj0 = blockIdx.x * TJ, ti0 = blockIdx.y * TI;
    const int b = blockIdx.z / NSPL;
    const int nt0 = (blockIdx.z % NSPL) * NTb;
    const int tid = threadIdx.x;
    if (BLDS) {
        for (int u2 = tid; u2 < TAPS * ICK * NTb * 64; u2 += 512) {
            int l2 = u2 & 63;
            int rest = u2 >> 6;
            int nt = rest % NTb;
            int qk = rest / NTb;
            ((bf16x8*)Bs)[u2] = ((const bf16x8*)Bp)[(qk * NTF + nt0 + nt) * 64 + l2];
        }
    }
    for (int u2 = tid; u2 < LR * LC * NOCT; u2 += 512) {
        int oct = u2 % NOCT;
        int hp = u2 / NOCT;
        int hr = hp / LC, hc = hp % LC;
        int gi = ti0 + hr - PH, gj = tj0 + hc - PW;
        bf16x8 v = {};
        if (gi >= 0 && gi < H && gj >= 0 && gj < W) {
            const short* s = (oct < 8) ? inA : inB;
            v = *(const bf16x8*)(s + (size_t)(b * HW + gi * W + gj) * 64 +
                                 (oct & 7) * 8);
        }
        int byte = hp * ICB + oct * 16;
        byte ^= ((byte >> LS) & 7) << 4;
        *(bf16x8*)(Xs + byte) = v;
    }
    __syncthreads();
    const int wave = tid >> 6, l = tid & 63;
    const int r = l & 15, q = l >> 4;
    const int mt0 = wave * 2;
    int p0 = mt0 * 16 + r, p1 = p0 + 16;
    int li0 = p0 >> 5, lj0 = p0 & 31, li1 = p1 >> 5, lj1 = p1 & 31;
    f32x4 acc[2][NTb] = {};
#pragma unroll
    for (int t = 0; t < TAPS; ++t) {
        const int u = t / KW, v = t % KW;
        int hp0 = (li0 + u) * LC + (lj0 + v);
        int hp1 = (li1 + u) * LC + (lj1 + v);
#pragma unroll
        for (int kk = 0; kk < ICK; ++kk) {
            int ab0 = hp0 * ICB + kk * 64 + q * 16;
            ab0 ^= ((ab0 >> LS) & 7) << 4;
            int ab1 = hp1 * ICB + kk * 64 + q * 16;
            ab1 ^= ((ab1 >> LS) & 7) << 4;
            bf16x8 a0 = *(const bf16x8*)(Xs + ab0);
            bf16x8 a1 = *(const bf16x8*)(Xs + ab1);
            const short* bbase =
                BLDS ? (const short*)Bs + (t * ICK + kk) * NTb * 512 + l * 8
                     : Bp + ((t * ICK + kk) * NTF + nt0) * 512 + l * 8;
#pragma unroll
            for (int nt = 0; nt < NTb; ++nt) {
                bf16x8 bv = *(const bf16x8*)(bbase + nt * 512);
                acc[0][nt] =
                    __builtin_amdgcn_mfma_f32_16x16x32_bf16(a0, bv, acc[0][nt], 0, 0, 0);
                acc[1][nt] =
                    __builtin_amdgcn_mfma_f32_16x16x32_bf16(a1, bv, acc[1][nt], 0, 0, 0);
            }
        }
    }
    const int col = l & 15;
#pragma unroll
    for (int mt = 0; mt < 2; ++mt)
#pragma unroll
        for (int nt = 0; nt < NTb; ++nt) {
            int oc = (nt0 + nt) * 16 + col;
            float bs = (oc < OC) ? bias[oc] : 0.f;
#pragma unroll
            for (int j = 0; j < 4; ++j) {
                int p = (mt0 + mt) * 16 + q * 4 + j;
                int gi = ti0 + (p >> 5), gj = tj0 + (p & 31);
                float val = acc[mt][nt][j] + bs;
                if (OMODE == 0) {
                    val = leakyf(val);
                    *((short*)outp + (size_t)(b * HW + gi * W + gj) * 64 + oc) =
                        f2bf(val);
                } else if (OMODE == 1) {
                    if (oc < 72)
                        *((short*)outp + (size_t)(b * HW + gi * W + gj) * 72 + oc) =
                            f2bf(val);
                } else {
                    val = leakyf(val);
                    *((float*)outp + (size_t)(b * 64 + oc) * HW + gi * W + gj) = val;
                }
            }
        }
}

// ---- correlation, wave-per-pixel: lane = channel, butterfly reduce ---------
// S[b][d][y][x] on the 98x98 padded grid; all bound checks wave-uniform.
__global__ __launch_bounds__(256) void k_corr_w(const float* __restrict__ nrT,
                                                float* __restrict__ S) {
    const int gw = blockIdx.x * 4 + (threadIdx.x >> 6);
    const int lane = threadIdx.x & 63;
    const int x = gw % 98;
    const int y = (gw / 98) % 98;
    const int b = gw / (98 * 98);
    const int f1i = y - 1, f1j = x - 1;
    const bool f1ok = (f1i >= 0 && f1i < H && f1j >= 0 && f1j < W);
    float v1 = 0.f;
    if (f1ok) v1 = nrT[((size_t)(b * HW + f1i * W + f1j)) * 64 + lane];
    float keep = 0.f;
    for (int d = 0; d < 49; ++d) {
        int f2i = y + d / 7 - 4, f2j = x + d % 7 - 4;
        float r = 0.f;
        if (f1ok && f2i >= 0 && f2i < H && f2j >= 0 && f2j < W) {
            float v2 = nrT[((size_t)(b * HW + f2i * W + f2j)) * 64 + lane];
            r = v1 * v2;
            r += __shfl_xor(r, 1);
            r += __shfl_xor(r, 2);
            r += __shfl_xor(r, 4);
            r += __shfl_xor(r, 8);
            r += __shfl_xor(r, 16);
            r += __shfl_xor(r, 32);
        }
        if (lane == d) keep = r;
    }
    if (lane < 49) S[((size_t)(b * 49 + lane)) * (98 * 98) + y * 98 + x] = keep;
}

// ---- 3x3 window-sum per displacement + top-3 (stable: strict >) ------------
__global__ void k_topk(const float* __restrict__ S, int* __restrict__ idx3) {
    int p = blockIdx.x * 256 + threadIdx.x;
    if (p >= BATCH * HW) return;
    int b = p / HW, i = (p % HW) / W, j = p % W;
    float v0 = -1e30f, v1 = -1e30f, v2 = -1e30f;
    int d0 = 0, d1 = 0, d2 = 0;
    for (int d = 0; d < 49; ++d) {
        const float* s = S + ((b * 49 + d) * 98 + i) * 98 + j;
        float v = 0.f;
#pragma unroll
        for (int u = 0; u < 3; ++u)
#pragma unroll
            for (int vv = 0; vv < 3; ++vv) v += s[u * 98 + vv];
        if (v > v0) {
            v2 = v1; d2 = d1; v1 = v0; d1 = d0; v0 = v; d0 = d;
        } else if (v > v1) {
            v2 = v1; d2 = d1; v1 = v; d1 = d;
        } else if (v > v2) {
            v2 = v; d2 = d;
        }
    }
    idx3[p * 3 + 0] = d0;
    idx3[p * 3 + 1] = d1;
    idx3[p * 3 + 2] = d2;
}

// ---- pack wnn raw taps into MFMA-B fragments -------------------------------
// B2[nt(4)][n(3)][h2(2)][tap(9)][lane(64)][e(8)]; oc=nt*16+(l&15),
// c=h2*32+(l>>4)*8+e, weight = wnn[oc, n*64+c, u, v], tap=(u*3+v)
__global__ void k_bswz2(const float* __restrict__ wnn, short* __restrict__ B2) {
    int i = blockIdx.x * 256 + threadIdx.x;
    if (i >= 4 * 3 * 2 * 9 * 512) return;
    int e = i & 7, l = (i >> 3) & 63;
    int t = (i >> 9) % 9;
    int h2 = (i / (512 * 9)) % 2;
    int n = (i / (512 * 9 * 2)) % 3;
    int nt = i / (512 * 9 * 2 * 3);
    int oc = nt * 16 + (l & 15);
    int c = h2 * 32 + (l >> 4) * 8 + e;
    int u = t / 3, v = t % 3;
    B2[i] = f2bf(wnn[((oc * 192 + n * 64 + c) * 3 + u) * 3 + v]);
}

// ---- MFMA gather-conv + mask reduce (raw-tap B, acc[yx] selection) ---------
__global__ __launch_bounds__(512) void k_agg_mfma(
    const short* __restrict__ refT, const int* __restrict__ idx3,
    const short* __restrict__ B2, const float* __restrict__ bnn,
    const short* __restrict__ maskT, short* __restrict__ agg) {
    constexpr int PX = 32;
    __shared__ short A_lds[2 * 54 * 64 * 8];  // 110,592 B
    __shared__ int sd[PX][NBR];
    const int p0 = blockIdx.x * PX;
    const int b = p0 / HW;
    const int i0 = (p0 % HW) / W;
    const int j0 = p0 % W;
    const int tid = threadIdx.x;
    if (tid < PX * NBR)
        sd[tid / NBR][tid % NBR] = idx3[(p0 + tid / NBR) * NBR + tid % NBR];
    __syncthreads();
    for (int u = tid; u < PX * NBR * 9 * 8; u += 512) {
        int oct = u & 7;
        int q = u >> 3;
        int rs = q % 9;
        int w2 = q / 9;
        int n = w2 % 3;
        int px = w2 / 3;
        int d = sd[px][n];
        int gi = i0 + d / 7 + rs / 3 - 4;
        int gj = j0 + px + d % 7 + rs % 3 - 4;
        bf16x8 val = {};
        if (gi >= 0 && gi < H && gj >= 0 && gj < W)
            val = *(const bf16x8*)(refT + ((size_t)(b * HW + gi * W + gj)) * 64 +
                                   oct * 8);
        int kb = (n * 9 + rs) * 64 + oct * 8;
        int chunk = (((px >> 4) * 54 + (kb >> 5)) << 6) + (((kb >> 3) & 3) << 4) +
                    (px & 15);
        int byte = chunk << 4;
        byte ^= ((byte >> 8) & 7) << 4;
        *(bf16x8*)((char*)A_lds + byte) = val;
    }
    __syncthreads();
    const int wave = tid >> 6;
    const int lane = tid & 63;
    const int w = wave & 3;      // oc slice
    const int half = wave >> 2;  // pixel group
    f32x4 acc[9] = {};
    const short* Bw = B2 + (size_t)w * (3 * 2 * 9 * 512) + lane * 8;
    const int abase = ((half * 54) * 64 + lane) << 4;
    for (int n = 0; n < 3; ++n) {
#pragma unroll
        for (int h2 = 0; h2 < 2; ++h2) {
            const short* bb = Bw + (n * 2 + h2) * 9 * 512;
            bf16x8 bv[9];
#pragma unroll
            for (int t = 0; t < 9; ++t) bv[t] = *(const bf16x8*)(bb + t * 512);
#pragma unroll
            for (int rs = 0; rs < 9; ++rs) {
                const int kk = (n * 9 + rs) * 2 + h2;
                int ab = abase + (kk << 10);
                ab ^= ((ab >> 8) & 7) << 4;
                bf16x8 a = *(const bf16x8*)((char*)A_lds + ab);
#pragma unroll
                for (int t = 0; t < 9; ++t) {
                    const int y = rs / 3 - t / 3 + 1;
                    const int x = rs % 3 - t % 3 + 1;
                    if (y >= 0 && y < 3 && x >= 0 && x < 3)
                        acc[y * 3 + x] = __builtin_amdgcn_mfma_f32_16x16x32_bf16(
                            a, bv[t], acc[y * 3 + x], 0, 0, 0);
                }
            }
        }
    }
    const int oc = w * 16 + (lane & 15);
    const float bn = bnn[oc];
    const int mrow = (lane >> 4) * 4;
#pragma unroll
    for (int j = 0; j < 4; ++j) {
        int px = half * 16 + mrow + j;
        int ij = i0 * W + j0 + px;
        const short* mb = maskT + (size_t)(b * HW + ij) * 72 + (oc >> 3) * 9;
        float sacc = 0.f;
#pragma unroll
        for (int yx = 0; yx < 9; ++yx) {
            float gv = leakyf(acc[yx][j] + bn);
            sacc += gv * bf2f(mb[yx]);
        }
        agg[(size_t)(b * HW + ij) * 64 + oc] = f2bf(leakyf(sacc));
    }
}

extern "C" void kernel_launch(void* const* d_in, const int* in_sizes, int n_in,
                              void* d_out, int out_size, void* d_ws,
                              size_t ws_size, hipStream_t stream) {
    const float* ref = (const float*)d_in[0];
    const float* w1 = (const float*)d_in[1];
    const float* b1 = (const float*)d_in[2];
    const float* w2 = (const float*)d_in[3];
    const float* b2 = (const float*)d_in[4];
    const float* w3 = (const float*)d_in[5];
    const float* b3 = (const float*)d_in[6];
    const float* w4 = (const float*)d_in[7];
    const float* b4 = (const float*)d_in[8];
    const float* wm = (const float*)d_in[9];
    const float* bm = (const float*)d_in[10];
    const float* wnn = (const float*)d_in[11];
    const float* bnn = (const float*)d_in[12];
    const float* wf = (const float*)d_in[13];
    const float* bf = (const float*)d_in[14];

    char* ws = (char*)d_ws;
    constexpr size_t O_NRT = 0;
    constexpr size_t O_S = O_NRT + (size_t)BATCH * HW * 64 * 4;
    constexpr size_t O_REFT = O_S + (size_t)BATCH * 49 * 98 * 98 * 4;
    constexpr size_t O_X1 = O_REFT + (size_t)BATCH * HW * 64 * 2;
    constexpr size_t O_X2 = O_X1 + (size_t)BATCH * HW * 64 * 2;
    constexpr size_t O_MASKT = O_X2 + (size_t)BATCH * HW * 64 * 2;
    constexpr size_t O_IDX = O_MASKT + (size_t)BATCH * HW * 72 * 2;
    constexpr size_t O_P1 = O_IDX + (size_t)BATCH * HW * 3 * 4;
    constexpr size_t O_P2 = O_P1 + 73728 * 2;
    constexpr size_t O_P3 = O_P2 + 73728 * 2;
    constexpr size_t O_P4 = O_P3 + 28672 * 2;
    constexpr size_t O_PM = O_P4 + 28672 * 2;
    constexpr size_t O_PF = O_PM + 46080 * 2;

    float* NRT = (float*)(ws + O_NRT);
    float* S = (float*)(ws + O_S);
    short* BSWZ2 = (short*)(ws + O_S);  // aliased: written after topk
    short* REFT = (short*)(ws + O_REFT);
    short* X1 = (short*)(ws + O_X1);
    short* X2 = (short*)(ws + O_X2);
    short* MASKT = (short*)(ws + O_MASKT);
    int* IDX = (int*)(ws + O_IDX);
    short* P1 = (short*)(ws + O_P1);
    short* P2 = (short*)(ws + O_P2);
    short* P3 = (short*)(ws + O_P3);
    short* P4 = (short*)(ws + O_P4);
    short* PM = (short*)(ws + O_PM);
    short* PF = (short*)(ws + O_PF);

    // input prep + weight packing
    k_pre<<<(BATCH * HW + 255) / 256, 256, 0, stream>>>(ref, REFT, NRT);
    k_prep<<<144, 256, 0, stream>>>(w1, P1, 64, 64, 128, 3, 3, 4, 1, 36864);
    k_prep<<<144, 256, 0, stream>>>(w2, P2, 64, 64, 64, 3, 3, 4, 0, 36864);
    k_prep<<<112, 256, 0, stream>>>(w3, P3, 64, 64, 64, 7, 1, 4, 0, 28672);
    k_prep<<<112, 256, 0, stream>>>(w4, P4, 64, 64, 64, 1, 7, 4, 0, 28672);
    k_prep<<<180, 256, 0, stream>>>(wm, PM, 72, 64, 64, 3, 3, 5, 0, 46080);
    k_prep<<<288, 256, 0, stream>>>(wf, PF, 64, 128, 128, 3, 3, 4, 0, 73728);

    dim3 cgrid2(3, 12, BATCH * 2);
    dim3 cgrid1(3, 12, BATCH);
    // mask branch (MFMA convs, bf16 channel-last chain, OC split x2)
    k_cmfma<3, 3, 64, 64, 0, true, 2><<<cgrid2, 512, 0, stream>>>(REFT, nullptr, P1, b1, X1);
    k_cmfma<3, 3, 64, 64, 0, true, 2><<<cgrid2, 512, 0, stream>>>(X1, nullptr, P2, b2, X2);
    k_cmfma<7, 1, 64, 64, 0, true, 2><<<cgrid2, 512, 0, stream>>>(X2, nullptr, P3, b3, X1);
    k_cmfma<1, 7, 64, 64, 0, true, 2><<<cgrid2, 512, 0, stream>>>(X1, nullptr, P4, b4, X2);
    k_cmfma<3, 3, 64, 72, 1, true, 1><<<cgrid1, 512, 0, stream>>>(X2, nullptr, PM, bm, MASKT);

    // correlation branch: wave-per-pixel, coalesced channel loads
    k_corr_w<<<BATCH * 98 * 98 / 4, 256, 0, stream>>>(NRT, S);
    k_topk<<<BATCH * HW / 256, 256, 0, stream>>>(S, IDX);

    // raw-tap W2 pack (into dead S region)
    k_bswz2<<<432, 256, 0, stream>>>(wnn, BSWZ2);

    // MFMA gather-conv + mask-weighted aggregate -> X1 (bf16 ch-last)
    k_agg_mfma<<<BATCH * HW / 32, 512, 0, stream>>>(REFT, IDX, BSWZ2, bnn, MASKT, X1);

    // final fusion conv: concat([ref, agg]) -> NCHW fp32 out
    k_cmfma<3, 3, 128, 64, 2, false, 1><<<cgrid1, 512, 0, stream>>>(REFT, X1, PF, bf, d_out);
}

// Round 7
// 237.212 us; speedup vs baseline: 1.4340x; 1.4340x over previous
//
#include <hip/hip_runtime.h>
#include <hip/hip_bf16.h>

constexpr int BATCH = 4;
constexpr int H = 96, W = 96, HW = H * W;
constexpr int NBR = 3;

using bf16x8 = __attribute__((ext_vector_type(8))) short;  // 8 bf16 in 4 VGPRs
using f32x4 = __attribute__((ext_vector_type(4))) float;

static __device__ __forceinline__ float leakyf(float x) {
    return x >= 0.f ? x : 0.1f * x;
}

static __device__ __forceinline__ short f2bf(float x) {
    __hip_bfloat16 h = __float2bfloat16(x);
    return *reinterpret_cast<short*>(&h);
}

static __device__ __forceinline__ float bf2f(short s) {
    __hip_bfloat16 h = *reinterpret_cast<__hip_bfloat16*>(&s);
    return __bfloat162float(h);
}

// ---- fused: ref NCHW fp32 -> REFT (bf16 ch-last) + NRN (normalized NCHW) ---
__global__ __launch_bounds__(256) void k_pre(const float* __restrict__ ref,
                                             short* __restrict__ reft,
                                             float* __restrict__ nrn) {
    int p = blockIdx.x * 256 + threadIdx.x;
    if (p >= BATCH * HW) return;
    int b = p / HW, ij = p % HW;
    const float* src = ref + b * 64 * HW + ij;
    float v[64];
    float ss = 0.f;
#pragma unroll
    for (int c = 0; c < 64; ++c) {
        v[c] = src[c * HW];
        ss += v[c] * v[c];
    }
    float inv = 1.f / fmaxf(sqrtf(ss), 1e-12f);
    short* rd = reft + (size_t)p * 64;
#pragma unroll
    for (int cc = 0; cc < 8; ++cc) {
        bf16x8 o;
#pragma unroll
        for (int j = 0; j < 8; ++j) o[j] = f2bf(v[cc * 8 + j]);
        *(bf16x8*)(rd + cc * 8) = o;
    }
    float* nd = nrn + b * 64 * HW + ij;
#pragma unroll
    for (int c = 0; c < 64; ++c) nd[c * HW] = v[c] * inv;
}

// ---- pack conv weights (OIHW fp32) into MFMA-B fragment layout -------------
// dst[tap][kk][nt][lane][e]; ic = kk*32+(l>>4)*8+e, oc = nt*16+(l&15)
__global__ void k_prep(const float* __restrict__ src, short* __restrict__ dst,
                       int OC, int ICt, int ICsrc, int KH, int KW, int NT,
                       int fold, int total) {
    int i = blockIdx.x * 256 + threadIdx.x;
    if (i >= total) return;
    int e = i & 7, l = (i >> 3) & 63;
    int rest = i >> 9;
    int nt = rest % NT;
    rest /= NT;
    int ICK = ICt >> 5;
    int kk = rest % ICK;
    int tap = rest / ICK;
    int ic = kk * 32 + (l >> 4) * 8 + e;
    int oc = nt * 16 + (l & 15);
    int u = tap / KW, v = tap % KW;
    float val = 0.f;
    if (oc < OC) {
        val = src[((oc * ICsrc + ic) * KH + u) * KW + v];
        if (fold) val += src[((oc * ICsrc + 64 + ic) * KH + u) * KW + v];
    }
    dst[i] = f2bf(val);
}

// ---- channel-last bf16 implicit-GEMM conv ----------------------------------
// tile 8x32 px, 8 waves x (2 Mtiles x NTb Ntiles). X staged in LDS (XOR swz),
// B staged in LDS when BLDS, else streamed. NSPL: split OC across blocks.
// OMODE 0: bf16 ch-last + leaky; 1: bf16 ch-last 72 (no act); 2: NCHW fp32 + leaky
template <int KH, int KW, int IC, int OC, int OMODE, bool BLDS, int NSPL>
__global__ __launch_bounds__(512) void k_cmfma(
    const short* __restrict__ inA, const short* __restrict__ inB,
    const short* __restrict__ Bp, const float* __restrict__ bias,
    void* __restrict__ outp) {
    constexpr int TI = 8, TJ = 32;
    constexpr int PH = (KH - 1) / 2, PW = (KW - 1) / 2;
    constexpr int LR = TI + KH - 1, LC = TJ + KW - 1;
    constexpr int ICB = IC * 2;
    constexpr int LS = (ICB == 128) ? 7 : 8;
    constexpr int ICK = IC / 32;
    constexpr int NTF = (OC + 15) / 16;
    constexpr int NTb = NTF / NSPL;
    constexpr int TAPS = KH * KW;
    constexpr int NOCT = ICB / 16;
    __shared__ char Xs[LR * LC * ICB];
    __shared__ short Bs[BLDS ? TAPS * ICK * NTb * 512 : 8];
    const int tj0 = blockIdx.x * TJ, ti0 = blockIdx.y * TI;
    const int b = blockIdx.z / NSPL;
    const int nt0 = (blockIdx.z % NSPL) * NTb;
    const int tid = threadIdx.x;
    if (BLDS) {
        for (int u2 = tid; u2 < TAPS * ICK * NTb * 64; u2 += 512) {
            int l2 = u2 & 63;
            int rest = u2 >> 6;
            int nt = rest % NTb;
            int qk = rest / NTb;
            ((bf16x8*)Bs)[u2] = ((const bf16x8*)Bp)[(qk * NTF + nt0 + nt) * 64 + l2];
        }
    }
    for (int u2 = tid; u2 < LR * LC * NOCT; u2 += 512) {
        int oct = u2 % NOCT;
        int hp = u2 / NOCT;
        int hr = hp / LC, hc = hp % LC;
        int gi = ti0 + hr - PH, gj = tj0 + hc - PW;
        bf16x8 v = {};
        if (gi >= 0 && gi < H && gj >= 0 && gj < W) {
            const short* s = (oct < 8) ? inA : inB;
            v = *(const bf16x8*)(s + (size_t)(b * HW + gi * W + gj) * 64 +
                                 (oct & 7) * 8);
        }
        int byte = hp * ICB + oct * 16;
        byte ^= ((byte >> LS) & 7) << 4;
        *(bf16x8*)(Xs + byte) = v;
    }
    __syncthreads();
    const int wave = tid >> 6, l = tid & 63;
    const int r = l & 15, q = l >> 4;
    const int mt0 = wave * 2;
    int p0 = mt0 * 16 + r, p1 = p0 + 16;
    int li0 = p0 >> 5, lj0 = p0 & 31, li1 = p1 >> 5, lj1 = p1 & 31;
    f32x4 acc[2][NTb] = {};
#pragma unroll
    for (int t = 0; t < TAPS; ++t) {
        const int u = t / KW, v = t % KW;
        int hp0 = (li0 + u) * LC + (lj0 + v);
        int hp1 = (li1 + u) * LC + (lj1 + v);
#pragma unroll
        for (int kk = 0; kk < ICK; ++kk) {
            int ab0 = hp0 * ICB + kk * 64 + q * 16;
            ab0 ^= ((ab0 >> LS) & 7) << 4;
            int ab1 = hp1 * ICB + kk * 64 + q * 16;
            ab1 ^= ((ab1 >> LS) & 7) << 4;
            bf16x8 a0 = *(const bf16x8*)(Xs + ab0);
            bf16x8 a1 = *(const bf16x8*)(Xs + ab1);
            const short* bbase =
                BLDS ? (const short*)Bs + (t * ICK + kk) * NTb * 512 + l * 8
                     : Bp + ((t * ICK + kk) * NTF + nt0) * 512 + l * 8;
#pragma unroll
            for (int nt = 0; nt < NTb; ++nt) {
                bf16x8 bv = *(const bf16x8*)(bbase + nt * 512);
                acc[0][nt] =
                    __builtin_amdgcn_mfma_f32_16x16x32_bf16(a0, bv, acc[0][nt], 0, 0, 0);
                acc[1][nt] =
                    __builtin_amdgcn_mfma_f32_16x16x32_bf16(a1, bv, acc[1][nt], 0, 0, 0);
            }
        }
    }
    const int col = l & 15;
#pragma unroll
    for (int mt = 0; mt < 2; ++mt)
#pragma unroll
        for (int nt = 0; nt < NTb; ++nt) {
            int oc = (nt0 + nt) * 16 + col;
            float bs = (oc < OC) ? bias[oc] : 0.f;
#pragma unroll
            for (int j = 0; j < 4; ++j) {
                int p = (mt0 + mt) * 16 + q * 4 + j;
                int gi = ti0 + (p >> 5), gj = tj0 + (p & 31);
                float val = acc[mt][nt][j] + bs;
                if (OMODE == 0) {
                    val = leakyf(val);
                    *((short*)outp + (size_t)(b * HW + gi * W + gj) * 64 + oc) =
                        f2bf(val);
                } else if (OMODE == 1) {
                    if (oc < 72)
                        *((short*)outp + (size_t)(b * HW + gi * W + gj) * 72 + oc) =
                            f2bf(val);
                } else {
                    val = leakyf(val);
                    *((float*)outp + (size_t)(b * 64 + oc) * HW + gi * W + gj) = val;
                }
            }
        }
}

// ---- per-displacement dot map S[b][d][y][x], NCHW features -----------------
// lane <-> consecutive x: every channel load is a coalesced 256-B transaction.
__global__ void k_corr(const float* __restrict__ nr, float* __restrict__ S) {
    int idx = blockIdx.x * 256 + threadIdx.x;
    if (idx >= BATCH * 49 * 98 * 98) return;
    int x = idx % 98;
    int y = (idx / 98) % 98;
    int d = (idx / (98 * 98)) % 49;
    int b = idx / (98 * 98 * 49);
    int f1i = y - 1, f1j = x - 1;
    int f2i = y + d / 7 - 4, f2j = x + d % 7 - 4;
    float r = 0.f;
    if (f1i >= 0 && f1i < H && f1j >= 0 && f1j < W && f2i >= 0 && f2i < H &&
        f2j >= 0 && f2j < W) {
        const float* p1 = nr + b * 64 * HW + f1i * W + f1j;
        const float* p2 = nr + b * 64 * HW + f2i * W + f2j;
#pragma unroll 16
        for (int c = 0; c < 64; ++c) r = fmaf(p1[c * HW], p2[c * HW], r);
    }
    S[idx] = r;
}

// ---- 3x3 window-sum per displacement + top-3 (stable: strict >) ------------
__global__ void k_topk(const float* __restrict__ S, int* __restrict__ idx3) {
    int p = blockIdx.x * 256 + threadIdx.x;
    if (p >= BATCH * HW) return;
    int b = p / HW, i = (p % HW) / W, j = p % W;
    float v0 = -1e30f, v1 = -1e30f, v2 = -1e30f;
    int d0 = 0, d1 = 0, d2 = 0;
    for (int d = 0; d < 49; ++d) {
        const float* s = S + ((b * 49 + d) * 98 + i) * 98 + j;
        float v = 0.f;
#pragma unroll
        for (int u = 0; u < 3; ++u)
#pragma unroll
            for (int vv = 0; vv < 3; ++vv) v += s[u * 98 + vv];
        if (v > v0) {
            v2 = v1; d2 = d1; v1 = v0; d1 = d0; v0 = v; d0 = d;
        } else if (v > v1) {
            v2 = v1; d2 = d1; v1 = v; d1 = d;
        } else if (v > v2) {
            v2 = v; d2 = d;
        }
    }
    idx3[p * 3 + 0] = d0;
    idx3[p * 3 + 1] = d1;
    idx3[p * 3 + 2] = d2;
}

// ---- pack wnn raw taps into MFMA-B fragments -------------------------------
// B2[nt(4)][n(3)][h2(2)][tap(9)][lane(64)][e(8)]; oc=nt*16+(l&15),
// c=h2*32+(l>>4)*8+e, weight = wnn[oc, n*64+c, u, v], tap=(u*3+v)
__global__ void k_bswz2(const float* __restrict__ wnn, short* __restrict__ B2) {
    int i = blockIdx.x * 256 + threadIdx.x;
    if (i >= 4 * 3 * 2 * 9 * 512) return;
    int e = i & 7, l = (i >> 3) & 63;
    int t = (i >> 9) % 9;
    int h2 = (i / (512 * 9)) % 2;
    int n = (i / (512 * 9 * 2)) % 3;
    int nt = i / (512 * 9 * 2 * 3);
    int oc = nt * 16 + (l & 15);
    int c = h2 * 32 + (l >> 4) * 8 + e;
    int u = t / 3, v = t % 3;
    B2[i] = f2bf(wnn[((oc * 192 + n * 64 + c) * 3 + u) * 3 + v]);
}

// ---- MFMA gather-conv + mask reduce (raw-tap B, acc[yx] selection) ---------
__global__ __launch_bounds__(512) void k_agg_mfma(
    const short* __restrict__ refT, const int* __restrict__ idx3,
    const short* __restrict__ B2, const float* __restrict__ bnn,
    const short* __restrict__ maskT, short* __restrict__ agg) {
    constexpr int PX = 32;
    __shared__ short A_lds[2 * 54 * 64 * 8];  // 110,592 B
    __shared__ int sd[PX][NBR];
    const int p0 = blockIdx.x * PX;
    const int b = p0 / HW;
    const int i0 = (p0 % HW) / W;
    const int j0 = p0 % W;
    const int tid = threadIdx.x;
    if (tid < PX * NBR)
        sd[tid / NBR][tid % NBR] = idx3[(p0 + tid / NBR) * NBR + tid % NBR];
    __syncthreads();
    for (int u = tid; u < PX * NBR * 9 * 8; u += 512) {
        int oct = u & 7;
        int q = u >> 3;
        int rs = q % 9;
        int w2 = q / 9;
        int n = w2 % 3;
        int px = w2 / 3;
        int d = sd[px][n];
        int gi = i0 + d / 7 + rs / 3 - 4;
        int gj = j0 + px + d % 7 + rs % 3 - 4;
        bf16x8 val = {};
        if (gi >= 0 && gi < H && gj >= 0 && gj < W)
            val = *(const bf16x8*)(refT + ((size_t)(b * HW + gi * W + gj)) * 64 +
                                   oct * 8);
        int kb = (n * 9 + rs) * 64 + oct * 8;
        int chunk = (((px >> 4) * 54 + (kb >> 5)) << 6) + (((kb >> 3) & 3) << 4) +
                    (px & 15);
        int byte = chunk << 4;
        byte ^= ((byte >> 8) & 7) << 4;
        *(bf16x8*)((char*)A_lds + byte) = val;
    }
    __syncthreads();
    const int wave = tid >> 6;
    const int lane = tid & 63;
    const int w = wave & 3;      // oc slice
    const int half = wave >> 2;  // pixel group
    f32x4 acc[9] = {};
    const short* Bw = B2 + (size_t)w * (3 * 2 * 9 * 512) + lane * 8;
    const int abase = ((half * 54) * 64 + lane) << 4;
    for (int n = 0; n < 3; ++n) {
#pragma unroll
        for (int h2 = 0; h2 < 2; ++h2) {
            const short* bb = Bw + (n * 2 + h2) * 9 * 512;
            bf16x8 bv[9];
#pragma unroll
            for (int t = 0; t < 9; ++t) bv[t] = *(const bf16x8*)(bb + t * 512);
#pragma unroll
            for (int rs = 0; rs < 9; ++rs) {
                const int kk = (n * 9 + rs) * 2 + h2;
                int ab = abase + (kk << 10);
                ab ^= ((ab >> 8) & 7) << 4;
                bf16x8 a = *(const bf16x8*)((char*)A_lds + ab);
#pragma unroll
                for (int t = 0; t < 9; ++t) {
                    const int y = rs / 3 - t / 3 + 1;
                    const int x = rs % 3 - t % 3 + 1;
                    if (y >= 0 && y < 3 && x >= 0 && x < 3)
                        acc[y * 3 + x] = __builtin_amdgcn_mfma_f32_16x16x32_bf16(
                            a, bv[t], acc[y * 3 + x], 0, 0, 0);
                }
            }
        }
    }
    const int oc = w * 16 + (lane & 15);
    const float bn = bnn[oc];
    const int mrow = (lane >> 4) * 4;
#pragma unroll
    for (int j = 0; j < 4; ++j) {
        int px = half * 16 + mrow + j;
        int ij = i0 * W + j0 + px;
        const short* mb = maskT + (size_t)(b * HW + ij) * 72 + (oc >> 3) * 9;
        float sacc = 0.f;
#pragma unroll
        for (int yx = 0; yx < 9; ++yx) {
            float gv = leakyf(acc[yx][j] + bn);
            sacc += gv * bf2f(mb[yx]);
        }
        agg[(size_t)(b * HW + ij) * 64 + oc] = f2bf(leakyf(sacc));
    }
}

extern "C" void kernel_launch(void* const* d_in, const int* in_sizes, int n_in,
                              void* d_out, int out_size, void* d_ws,
                              size_t ws_size, hipStream_t stream) {
    const float* ref = (const float*)d_in[0];
    const float* w1 = (const float*)d_in[1];
    const float* b1 = (const float*)d_in[2];
    const float* w2 = (const float*)d_in[3];
    const float* b2 = (const float*)d_in[4];
    const float* w3 = (const float*)d_in[5];
    const float* b3 = (const float*)d_in[6];
    const float* w4 = (const float*)d_in[7];
    const float* b4 = (const float*)d_in[8];
    const float* wm = (const float*)d_in[9];
    const float* bm = (const float*)d_in[10];
    const float* wnn = (const float*)d_in[11];
    const float* bnn = (const float*)d_in[12];
    const float* wf = (const float*)d_in[13];
    const float* bf = (const float*)d_in[14];

    char* ws = (char*)d_ws;
    constexpr size_t O_NRN = 0;
    constexpr size_t O_S = O_NRN + (size_t)BATCH * HW * 64 * 4;
    constexpr size_t O_REFT = O_S + (size_t)BATCH * 49 * 98 * 98 * 4;
    constexpr size_t O_X1 = O_REFT + (size_t)BATCH * HW * 64 * 2;
    constexpr size_t O_X2 = O_X1 + (size_t)BATCH * HW * 64 * 2;
    constexpr size_t O_MASKT = O_X2 + (size_t)BATCH * HW * 64 * 2;
    constexpr size_t O_IDX = O_MASKT + (size_t)BATCH * HW * 72 * 2;
    constexpr size_t O_P1 = O_IDX + (size_t)BATCH * HW * 3 * 4;
    constexpr size_t O_P2 = O_P1 + 73728 * 2;
    constexpr size_t O_P3 = O_P2 + 73728 * 2;
    constexpr size_t O_P4 = O_P3 + 28672 * 2;
    constexpr size_t O_PM = O_P4 + 28672 * 2;
    constexpr size_t O_PF = O_PM + 46080 * 2;

    float* NRN = (float*)(ws + O_NRN);
    float* S = (float*)(ws + O_S);
    short* BSWZ2 = (short*)(ws + O_S);  // aliased: written after topk
    short* REFT = (short*)(ws + O_REFT);
    short* X1 = (short*)(ws + O_X1);
    short* X2 = (short*)(ws + O_X2);
    short* MASKT = (short*)(ws + O_MASKT);
    int* IDX = (int*)(ws + O_IDX);
    short* P1 = (short*)(ws + O_P1);
    short* P2 = (short*)(ws + O_P2);
    short* P3 = (short*)(ws + O_P3);
    short* P4 = (short*)(ws + O_P4);
    short* PM = (short*)(ws + O_PM);
    short* PF = (short*)(ws + O_PF);

    // input prep + weight packing
    k_pre<<<(BATCH * HW + 255) / 256, 256, 0, stream>>>(ref, REFT, NRN);
    k_prep<<<144, 256, 0, stream>>>(w1, P1, 64, 64, 128, 3, 3, 4, 1, 36864);
    k_prep<<<144, 256, 0, stream>>>(w2, P2, 64, 64, 64, 3, 3, 4, 0, 36864);
    k_prep<<<112, 256, 0, stream>>>(w3, P3, 64, 64, 64, 7, 1, 4, 0, 28672);
    k_prep<<<112, 256, 0, stream>>>(w4, P4, 64, 64, 64, 1, 7, 4, 0, 28672);
    k_prep<<<180, 256, 0, stream>>>(wm, PM, 72, 64, 64, 3, 3, 5, 0, 46080);
    k_prep<<<288, 256, 0, stream>>>(wf, PF, 64, 128, 128, 3, 3, 4, 0, 73728);

    dim3 cgrid2(3, 12, BATCH * 2);
    dim3 cgrid1(3, 12, BATCH);
    // mask branch (MFMA convs, bf16 channel-last chain, OC split x2)
    k_cmfma<3, 3, 64, 64, 0, true, 2><<<cgrid2, 512, 0, stream>>>(REFT, nullptr, P1, b1, X1);
    k_cmfma<3, 3, 64, 64, 0, true, 2><<<cgrid2, 512, 0, stream>>>(X1, nullptr, P2, b2, X2);
    k_cmfma<7, 1, 64, 64, 0, true, 2><<<cgrid2, 512, 0, stream>>>(X2, nullptr, P3, b3, X1);
    k_cmfma<1, 7, 64, 64, 0, true, 2><<<cgrid2, 512, 0, stream>>>(X1, nullptr, P4, b4, X2);
    k_cmfma<3, 3, 64, 72, 1, true, 1><<<cgrid1, 512, 0, stream>>>(X2, nullptr, PM, bm, MASKT);

    // correlation branch: NCHW per-thread dot (lane = x, coalesced)
    k_corr<<<(BATCH * 49 * 98 * 98 + 255) / 256, 256, 0, stream>>>(NRN, S);
    k_topk<<<BATCH * HW / 256, 256, 0, stream>>>(S, IDX);

    // raw-tap W2 pack (into dead S region)
    k_bswz2<<<432, 256, 0, stream>>>(wnn, BSWZ2);

    // MFMA gather-conv + mask-weighted aggregate -> X1 (bf16 ch-last)
    k_agg_mfma<<<BATCH * HW / 32, 512, 0, stream>>>(REFT, IDX, BSWZ2, bnn, MASKT, X1);

    // final fusion conv: concat([ref, agg]) -> NCHW fp32 out
    k_cmfma<3, 3, 128, 64, 2, false, 1><<<cgrid1, 512, 0, stream>>>(REFT, X1, PF, bf, d_out);
}

// Round 8
// 219.587 us; speedup vs baseline: 1.5491x; 1.0803x over previous
//
#include <hip/hip_runtime.h>
#include <hip/hip_bf16.h>

constexpr int BATCH = 4;
constexpr int H = 96, W = 96, HW = H * W;
constexpr int NBR = 3;

using bf16x8 = __attribute__((ext_vector_type(8))) short;  // 8 bf16 in 4 VGPRs
using f32x4 = __attribute__((ext_vector_type(4))) float;

static __device__ __forceinline__ float leakyf(float x) {
    return x >= 0.f ? x : 0.1f * x;
}

static __device__ __forceinline__ short f2bf(float x) {
    __hip_bfloat16 h = __float2bfloat16(x);
    return *reinterpret_cast<short*>(&h);
}

static __device__ __forceinline__ float bf2f(short s) {
    __hip_bfloat16 h = *reinterpret_cast<__hip_bfloat16*>(&s);
    return __bfloat162float(h);
}

// ---- fused: ref NCHW fp32 -> REFT (bf16 ch-last) + NRN (normalized NCHW) ---
__global__ __launch_bounds__(256) void k_pre(const float* __restrict__ ref,
                                             short* __restrict__ reft,
                                             float* __restrict__ nrn) {
    int p = blockIdx.x * 256 + threadIdx.x;
    if (p >= BATCH * HW) return;
    int b = p / HW, ij = p % HW;
    const float* src = ref + b * 64 * HW + ij;
    float v[64];
    float ss = 0.f;
#pragma unroll
    for (int c = 0; c < 64; ++c) {
        v[c] = src[c * HW];
        ss += v[c] * v[c];
    }
    float inv = 1.f / fmaxf(sqrtf(ss), 1e-12f);
    short* rd = reft + (size_t)p * 64;
#pragma unroll
    for (int cc = 0; cc < 8; ++cc) {
        bf16x8 o;
#pragma unroll
        for (int j = 0; j < 8; ++j) o[j] = f2bf(v[cc * 8 + j]);
        *(bf16x8*)(rd + cc * 8) = o;
    }
    float* nd = nrn + b * 64 * HW + ij;
#pragma unroll
    for (int c = 0; c < 64; ++c) nd[c * HW] = v[c] * inv;
}

// ---- pack conv weights (OIHW fp32) into MFMA-B fragment layout -------------
// dst[tap][kk][nt][lane][e]; ic = kk*32+(l>>4)*8+e, oc = nt*16+(l&15)
__global__ void k_prep(const float* __restrict__ src, short* __restrict__ dst,
                       int OC, int ICt, int ICsrc, int KH, int KW, int NT,
                       int fold, int total) {
    int i = blockIdx.x * 256 + threadIdx.x;
    if (i >= total) return;
    int e = i & 7, l = (i >> 3) & 63;
    int rest = i >> 9;
    int nt = rest % NT;
    rest /= NT;
    int ICK = ICt >> 5;
    int kk = rest % ICK;
    int tap = rest / ICK;
    int ic = kk * 32 + (l >> 4) * 8 + e;
    int oc = nt * 16 + (l & 15);
    int u = tap / KW, v = tap % KW;
    float val = 0.f;
    if (oc < OC) {
        val = src[((oc * ICsrc + ic) * KH + u) * KW + v];
        if (fold) val += src[((oc * ICsrc + 64 + ic) * KH + u) * KW + v];
    }
    dst[i] = f2bf(val);
}

// ---- channel-last bf16 implicit-GEMM conv ----------------------------------
// tile 8x32 px, 8 waves x (2 Mtiles x NTb Ntiles). X staged in LDS (XOR swz),
// B staged in LDS when BLDS, else streamed. NSPL: split OC across blocks.
// OMODE 0: bf16 ch-last + leaky; 1: bf16 ch-last 72 (no act); 2: NCHW fp32 + leaky
template <int KH, int KW, int IC, int OC, int OMODE, bool BLDS, int NSPL>
__global__ __launch_bounds__(512) void k_cmfma(
    const short* __restrict__ inA, const short* __restrict__ inB,
    const short* __restrict__ Bp, const float* __restrict__ bias,
    void* __restrict__ outp) {
    constexpr int TI = 8, TJ = 32;
    constexpr int PH = (KH - 1) / 2, PW = (KW - 1) / 2;
    constexpr int LR = TI + KH - 1, LC = TJ + KW - 1;
    constexpr int ICB = IC * 2;
    constexpr int LS = (ICB == 128) ? 7 : 8;
    constexpr int ICK = IC / 32;
    constexpr int NTF = (OC + 15) / 16;
    constexpr int NTb = NTF / NSPL;
    constexpr int TAPS = KH * KW;
    constexpr int NOCT = ICB / 16;
    __shared__ char Xs[LR * LC * ICB];
    __shared__ short Bs[BLDS ? TAPS * ICK * NTb * 512 : 8];
    const int tj0 = blockIdx.x * TJ, ti0 = blockIdx.y * TI;
    const int b = blockIdx.z / NSPL;
    const int nt0 = (blockIdx.z % NSPL) * NTb;
    const int tid = threadIdx.x;
    if (BLDS) {
        for (int u2 = tid; u2 < TAPS * ICK * NTb * 64; u2 += 512) {
            int l2 = u2 & 63;
            int rest = u2 >> 6;
            int nt = rest % NTb;
            int qk = rest / NTb;
            ((bf16x8*)Bs)[u2] = ((const bf16x8*)Bp)[(qk * NTF + nt0 + nt) * 64 + l2];
        }
    }
    for (int u2 = tid; u2 < LR * LC * NOCT; u2 += 512) {
        int oct = u2 % NOCT;
        int hp = u2 / NOCT;
        int hr = hp / LC, hc = hp % LC;
        int gi = ti0 + hr - PH, gj = tj0 + hc - PW;
        bf16x8 v = {};
        if (gi >= 0 && gi < H && gj >= 0 && gj < W) {
            const short* s = (oct < 8) ? inA : inB;
            v = *(const bf16x8*)(s + (size_t)(b * HW + gi * W + gj) * 64 +
                                 (oct & 7) * 8);
        }
        int byte = hp * ICB + oct * 16;
        byte ^= ((byte >> LS) & 7) << 4;
        *(bf16x8*)(Xs + byte) = v;
    }
    __syncthreads();
    const int wave = tid >> 6, l = tid & 63;
    const int r = l & 15, q = l >> 4;
    const int mt0 = wave * 2;
    int p0 = mt0 * 16 + r, p1 = p0 + 16;
    int li0 = p0 >> 5, lj0 = p0 & 31, li1 = p1 >> 5, lj1 = p1 & 31;
    f32x4 acc[2][NTb] = {};
#pragma unroll
    for (int t = 0; t < TAPS; ++t) {
        const int u = t / KW, v = t % KW;
        int hp0 = (li0 + u) * LC + (lj0 + v);
        int hp1 = (li1 + u) * LC + (lj1 + v);
#pragma unroll
        for (int kk = 0; kk < ICK; ++kk) {
            int ab0 = hp0 * ICB + kk * 64 + q * 16;
            ab0 ^= ((ab0 >> LS) & 7) << 4;
            int ab1 = hp1 * ICB + kk * 64 + q * 16;
            ab1 ^= ((ab1 >> LS) & 7) << 4;
            bf16x8 a0 = *(const bf16x8*)(Xs + ab0);
            bf16x8 a1 = *(const bf16x8*)(Xs + ab1);
            const short* bbase =
                BLDS ? (const short*)Bs + (t * ICK + kk) * NTb * 512 + l * 8
                     : Bp + ((t * ICK + kk) * NTF + nt0) * 512 + l * 8;
#pragma unroll
            for (int nt = 0; nt < NTb; ++nt) {
                bf16x8 bv = *(const bf16x8*)(bbase + nt * 512);
                acc[0][nt] =
                    __builtin_amdgcn_mfma_f32_16x16x32_bf16(a0, bv, acc[0][nt], 0, 0, 0);
                acc[1][nt] =
                    __builtin_amdgcn_mfma_f32_16x16x32_bf16(a1, bv, acc[1][nt], 0, 0, 0);
            }
        }
    }
    const int col = l & 15;
#pragma unroll
    for (int mt = 0; mt < 2; ++mt)
#pragma unroll
        for (int nt = 0; nt < NTb; ++nt) {
            int oc = (nt0 + nt) * 16 + col;
            float bs = (oc < OC) ? bias[oc] : 0.f;
#pragma unroll
            for (int j = 0; j < 4; ++j) {
                int p = (mt0 + mt) * 16 + q * 4 + j;
                int gi = ti0 + (p >> 5), gj = tj0 + (p & 31);
                float val = acc[mt][nt][j] + bs;
                if (OMODE == 0) {
                    val = leakyf(val);
                    *((short*)outp + (size_t)(b * HW + gi * W + gj) * 64 + oc) =
                        f2bf(val);
                } else if (OMODE == 1) {
                    if (oc < 72)
                        *((short*)outp + (size_t)(b * HW + gi * W + gj) * 72 + oc) =
                            f2bf(val);
                } else {
                    val = leakyf(val);
                    *((float*)outp + (size_t)(b * 64 + oc) * HW + gi * W + gj) = val;
                }
            }
        }
}

// ---- per-displacement dot map, NCHW, symmetry-halved -----------------------
// S[b][48-d][y+dy-3][x+dx-3] == S[b][d][y][x]; compute d<=24, mirror-write.
// Uncovered d>24 entries are structurally 0 (pre-zeroed by memset).
__global__ void k_corr_sym(const float* __restrict__ nr, float* __restrict__ S) {
    int idx = blockIdx.x * 256 + threadIdx.x;
    if (idx >= BATCH * 25 * 98 * 98) return;
    int x = idx % 98;
    int y = (idx / 98) % 98;
    int d = (idx / (98 * 98)) % 25;
    int b = idx / (98 * 98 * 25);
    int dy = d / 7, dx = d % 7;
    int f1i = y - 1, f1j = x - 1;
    int f2i = y + dy - 4, f2j = x + dx - 4;
    float r = 0.f;
    if (f1i >= 0 && f1i < H && f1j >= 0 && f1j < W && f2i >= 0 && f2i < H &&
        f2j >= 0 && f2j < W) {
        const float* p1 = nr + b * 64 * HW + f1i * W + f1j;
        const float* p2 = nr + b * 64 * HW + f2i * W + f2j;
#pragma unroll 16
        for (int c = 0; c < 64; ++c) r = fmaf(p1[c * HW], p2[c * HW], r);
    }
    S[((size_t)(b * 49 + d)) * (98 * 98) + y * 98 + x] = r;
    if (d < 24) {
        int y2 = y + dy - 3, x2 = x + dx - 3;
        if (y2 >= 0 && y2 < 98 && x2 >= 0 && x2 < 98)
            S[((size_t)(b * 49 + 48 - d)) * (98 * 98) + y2 * 98 + x2] = r;
    }
}

// ---- 3x3 window-sum per displacement + top-3 (stable: strict >) ------------
__global__ void k_topk(const float* __restrict__ S, int* __restrict__ idx3) {
    int p = blockIdx.x * 256 + threadIdx.x;
    if (p >= BATCH * HW) return;
    int b = p / HW, i = (p % HW) / W, j = p % W;
    float v0 = -1e30f, v1 = -1e30f, v2 = -1e30f;
    int d0 = 0, d1 = 0, d2 = 0;
    for (int d = 0; d < 49; ++d) {
        const float* s = S + ((b * 49 + d) * 98 + i) * 98 + j;
        float v = 0.f;
#pragma unroll
        for (int u = 0; u < 3; ++u)
#pragma unroll
            for (int vv = 0; vv < 3; ++vv) v += s[u * 98 + vv];
        if (v > v0) {
            v2 = v1; d2 = d1; v1 = v0; d1 = d0; v0 = v; d0 = d;
        } else if (v > v1) {
            v2 = v1; d2 = d1; v1 = v; d1 = d;
        } else if (v > v2) {
            v2 = v; d2 = d;
        }
    }
    idx3[p * 3 + 0] = d0;
    idx3[p * 3 + 1] = d1;
    idx3[p * 3 + 2] = d2;
}

// ---- pack wnn raw taps into MFMA-B fragments -------------------------------
// B2[nt(4)][n(3)][h2(2)][tap(9)][lane(64)][e(8)]; oc=nt*16+(l&15),
// c=h2*32+(l>>4)*8+e, weight = wnn[oc, n*64+c, u, v], tap=(u*3+v)
__global__ void k_bswz2(const float* __restrict__ wnn, short* __restrict__ B2) {
    int i = blockIdx.x * 256 + threadIdx.x;
    if (i >= 4 * 3 * 2 * 9 * 512) return;
    int e = i & 7, l = (i >> 3) & 63;
    int t = (i >> 9) % 9;
    int h2 = (i / (512 * 9)) % 2;
    int n = (i / (512 * 9 * 2)) % 3;
    int nt = i / (512 * 9 * 2 * 3);
    int oc = nt * 16 + (l & 15);
    int c = h2 * 32 + (l >> 4) * 8 + e;
    int u = t / 3, v = t % 3;
    B2[i] = f2bf(wnn[((oc * 192 + n * 64 + c) * 3 + u) * 3 + v]);
}

// ---- MFMA gather-conv + mask reduce, pipelined over neighbors --------------
// A double-buffered per neighbor (2 x 36,864 B); gather loads for n+1 issued
// before compute(n) (async-STAGE split), ds_write after. 2 blocks/CU.
__global__ __launch_bounds__(512, 4) void k_agg_mfma(
    const short* __restrict__ refT, const int* __restrict__ idx3,
    const short* __restrict__ B2, const float* __restrict__ bnn,
    const short* __restrict__ maskT, short* __restrict__ agg) {
    constexpr int PX = 32;
    constexpr int BUFB = 2 * 18 * 64 * 8 * 2;  // 36,864 bytes per buffer
    __shared__ short A_lds[2 * 2 * 18 * 64 * 8];  // 73,728 B
    __shared__ int sd[PX][NBR];
    const int p0 = blockIdx.x * PX;
    const int b = p0 / HW;
    const int i0 = (p0 % HW) / W;
    const int j0 = p0 % W;
    const int tid = threadIdx.x;
    if (tid < PX * NBR)
        sd[tid / NBR][tid % NBR] = idx3[(p0 + tid / NBR) * NBR + tid % NBR];
    __syncthreads();

    bf16x8 greg[5];
    int gbyte[5];

    auto LD = [&](int n, int buf) {
#pragma unroll
        for (int i = 0; i < 5; ++i) {
            int u = tid + i * 512;
            if (u < PX * 9 * 8) {
                int oct = u & 7;
                int q = u >> 3;
                int rs = q % 9;
                int px = q / 9;
                int d = sd[px][n];
                int gi = i0 + d / 7 + rs / 3 - 4;
                int gj = j0 + px + d % 7 + rs % 3 - 4;
                bf16x8 val = {};
                if (gi >= 0 && gi < H && gj >= 0 && gj < W)
                    val = *(const bf16x8*)(refT +
                                           (size_t)(b * HW + gi * W + gj) * 64 +
                                           oct * 8);
                int kkl = rs * 2 + (oct >> 2);
                int chunk = ((px >> 4) * 18 + kkl) * 64 + (oct & 3) * 16 + (px & 15);
                int byte = buf * BUFB + (chunk << 4);
                byte ^= ((byte >> 8) & 7) << 4;
                greg[i] = val;
                gbyte[i] = byte;
            } else {
                gbyte[i] = -1;
            }
        }
    };
    auto WR = [&]() {
#pragma unroll
        for (int i = 0; i < 5; ++i)
            if (gbyte[i] >= 0) *(bf16x8*)((char*)A_lds + gbyte[i]) = greg[i];
    };

    const int wave = tid >> 6;
    const int lane = tid & 63;
    const int w = wave & 3;      // oc slice
    const int half = wave >> 2;  // pixel group
    f32x4 acc[9] = {};
    const short* Bw = B2 + (size_t)w * (3 * 2 * 9 * 512) + lane * 8;

    auto COMPUTE = [&](int n, int buf) {
#pragma unroll
        for (int h2 = 0; h2 < 2; ++h2) {
            const short* bb = Bw + (n * 2 + h2) * 9 * 512;
            bf16x8 bv[9];
#pragma unroll
            for (int t = 0; t < 9; ++t) bv[t] = *(const bf16x8*)(bb + t * 512);
#pragma unroll
            for (int rs = 0; rs < 9; ++rs) {
                int kkl = rs * 2 + h2;
                int ab = buf * BUFB + ((((half * 18 + kkl) << 6) + lane) << 4);
                ab ^= ((ab >> 8) & 7) << 4;
                bf16x8 a = *(const bf16x8*)((char*)A_lds + ab);
#pragma unroll
                for (int t = 0; t < 9; ++t) {
                    const int y = rs / 3 - t / 3 + 1;
                    const int x = rs % 3 - t % 3 + 1;
                    if (y >= 0 && y < 3 && x >= 0 && x < 3)
                        acc[y * 3 + x] = __builtin_amdgcn_mfma_f32_16x16x32_bf16(
                            a, bv[t], acc[y * 3 + x], 0, 0, 0);
                }
            }
        }
    };

    // pipeline: LD(n+1) issued before COMPUTE(n); WR lands after
    LD(0, 0);
    WR();
    LD(1, 1);
    __syncthreads();          // buf0 ready
    COMPUTE(0, 0);
    WR();                     // write buf1
    LD(2, 0);
    __syncthreads();          // buf1 ready; all done reading buf0
    COMPUTE(1, 1);
    WR();                     // write buf0
    __syncthreads();          // buf0 ready
    COMPUTE(2, 0);

    const int oc = w * 16 + (lane & 15);
    const float bn = bnn[oc];
    const int mrow = (lane >> 4) * 4;
#pragma unroll
    for (int j = 0; j < 4; ++j) {
        int px = half * 16 + mrow + j;
        int ij = i0 * W + j0 + px;
        const short* mb = maskT + (size_t)(b * HW + ij) * 72 + (oc >> 3) * 9;
        float sacc = 0.f;
#pragma unroll
        for (int yx = 0; yx < 9; ++yx) {
            float gv = leakyf(acc[yx][j] + bn);
            sacc += gv * bf2f(mb[yx]);
        }
        agg[(size_t)(b * HW + ij) * 64 + oc] = f2bf(leakyf(sacc));
    }
}

extern "C" void kernel_launch(void* const* d_in, const int* in_sizes, int n_in,
                              void* d_out, int out_size, void* d_ws,
                              size_t ws_size, hipStream_t stream) {
    const float* ref = (const float*)d_in[0];
    const float* w1 = (const float*)d_in[1];
    const float* b1 = (const float*)d_in[2];
    const float* w2 = (const float*)d_in[3];
    const float* b2 = (const float*)d_in[4];
    const float* w3 = (const float*)d_in[5];
    const float* b3 = (const float*)d_in[6];
    const float* w4 = (const float*)d_in[7];
    const float* b4 = (const float*)d_in[8];
    const float* wm = (const float*)d_in[9];
    const float* bm = (const float*)d_in[10];
    const float* wnn = (const float*)d_in[11];
    const float* bnn = (const float*)d_in[12];
    const float* wf = (const float*)d_in[13];
    const float* bf = (const float*)d_in[14];

    char* ws = (char*)d_ws;
    constexpr size_t O_NRN = 0;
    constexpr size_t O_S = O_NRN + (size_t)BATCH * HW * 64 * 4;
    constexpr size_t O_REFT = O_S + (size_t)BATCH * 49 * 98 * 98 * 4;
    constexpr size_t O_X1 = O_REFT + (size_t)BATCH * HW * 64 * 2;
    constexpr size_t O_X2 = O_X1 + (size_t)BATCH * HW * 64 * 2;
    constexpr size_t O_MASKT = O_X2 + (size_t)BATCH * HW * 64 * 2;
    constexpr size_t O_IDX = O_MASKT + (size_t)BATCH * HW * 72 * 2;
    constexpr size_t O_P1 = O_IDX + (size_t)BATCH * HW * 3 * 4;
    constexpr size_t O_P2 = O_P1 + 73728 * 2;
    constexpr size_t O_P3 = O_P2 + 73728 * 2;
    constexpr size_t O_P4 = O_P3 + 28672 * 2;
    constexpr size_t O_PM = O_P4 + 28672 * 2;
    constexpr size_t O_PF = O_PM + 46080 * 2;

    float* NRN = (float*)(ws + O_NRN);
    float* S = (float*)(ws + O_S);
    short* BSWZ2 = (short*)(ws + O_S);  // aliased: written after topk
    short* REFT = (short*)(ws + O_REFT);
    short* X1 = (short*)(ws + O_X1);
    short* X2 = (short*)(ws + O_X2);
    short* MASKT = (short*)(ws + O_MASKT);
    int* IDX = (int*)(ws + O_IDX);
    short* P1 = (short*)(ws + O_P1);
    short* P2 = (short*)(ws + O_P2);
    short* P3 = (short*)(ws + O_P3);
    short* P4 = (short*)(ws + O_P4);
    short* PM = (short*)(ws + O_PM);
    short* PF = (short*)(ws + O_PF);

    // input prep + weight packing
    k_pre<<<(BATCH * HW + 255) / 256, 256, 0, stream>>>(ref, REFT, NRN);
    k_prep<<<144, 256, 0, stream>>>(w1, P1, 64, 64, 128, 3, 3, 4, 1, 36864);
    k_prep<<<144, 256, 0, stream>>>(w2, P2, 64, 64, 64, 3, 3, 4, 0, 36864);
    k_prep<<<112, 256, 0, stream>>>(w3, P3, 64, 64, 64, 7, 1, 4, 0, 28672);
    k_prep<<<112, 256, 0, stream>>>(w4, P4, 64, 64, 64, 1, 7, 4, 0, 28672);
    k_prep<<<180, 256, 0, stream>>>(wm, PM, 72, 64, 64, 3, 3, 5, 0, 46080);
    k_prep<<<288, 256, 0, stream>>>(wf, PF, 64, 128, 128, 3, 3, 4, 0, 73728);

    dim3 cgrid2(3, 12, BATCH * 2);
    dim3 cgrid1(3, 12, BATCH);
    // mask branch (MFMA convs, bf16 channel-last chain, OC split x2)
    k_cmfma<3, 3, 64, 64, 0, true, 2><<<cgrid2, 512, 0, stream>>>(REFT, nullptr, P1, b1, X1);
    k_cmfma<3, 3, 64, 64, 0, true, 2><<<cgrid2, 512, 0, stream>>>(X1, nullptr, P2, b2, X2);
    k_cmfma<7, 1, 64, 64, 0, true, 2><<<cgrid2, 512, 0, stream>>>(X2, nullptr, P3, b3, X1);
    k_cmfma<1, 7, 64, 64, 0, true, 2><<<cgrid2, 512, 0, stream>>>(X1, nullptr, P4, b4, X2);
    k_cmfma<3, 3, 64, 72, 1, true, 1><<<cgrid1, 512, 0, stream>>>(X2, nullptr, PM, bm, MASKT);

    // correlation: zero-fill d>24 planes, compute d<=24 + mirror write
    for (int b = 0; b < BATCH; ++b)
        hipMemsetAsync(S + ((size_t)(b * 49 + 25)) * 98 * 98,
                       0, (size_t)24 * 98 * 98 * 4, stream);
    k_corr_sym<<<(BATCH * 25 * 98 * 98 + 255) / 256, 256, 0, stream>>>(NRN, S);
    k_topk<<<BATCH * HW / 256, 256, 0, stream>>>(S, IDX);

    // raw-tap W2 pack (into dead S region)
    k_bswz2<<<432, 256, 0, stream>>>(wnn, BSWZ2);

    // MFMA gather-conv + mask-weighted aggregate -> X1 (bf16 ch-last)
    k_agg_mfma<<<BATCH * HW / 32, 512, 0, stream>>>(REFT, IDX, BSWZ2, bnn, MASKT, X1);

    // final fusion conv: concat([ref, agg]) -> NCHW fp32 out
    k_cmfma<3, 3, 128, 64, 2, false, 1><<<cgrid1, 512, 0, stream>>>(REFT, X1, PF, bf, d_out);
}

// Round 9
// 208.968 us; speedup vs baseline: 1.6278x; 1.0508x over previous
//
#include <hip/hip_runtime.h>
#include <hip/hip_bf16.h>

constexpr int BATCH = 4;
constexpr int H = 96, W = 96, HW = H * W;
constexpr int NBR = 3;

using bf16x8 = __attribute__((ext_vector_type(8))) short;  // 8 bf16 in 4 VGPRs
using f32x4 = __attribute__((ext_vector_type(4))) float;

static __device__ __forceinline__ float leakyf(float x) {
    return x >= 0.f ? x : 0.1f * x;
}

static __device__ __forceinline__ short f2bf(float x) {
    __hip_bfloat16 h = __float2bfloat16(x);
    return *reinterpret_cast<short*>(&h);
}

static __device__ __forceinline__ float bf2f(short s) {
    __hip_bfloat16 h = *reinterpret_cast<__hip_bfloat16*>(&s);
    return __bfloat162float(h);
}

// ---- fused: ref NCHW fp32 -> REFT (bf16 ch-last) + NRN (normalized NCHW) ---
__global__ __launch_bounds__(256) void k_pre(const float* __restrict__ ref,
                                             short* __restrict__ reft,
                                             float* __restrict__ nrn) {
    int p = blockIdx.x * 256 + threadIdx.x;
    if (p >= BATCH * HW) return;
    int b = p / HW, ij = p % HW;
    const float* src = ref + b * 64 * HW + ij;
    float v[64];
    float ss = 0.f;
#pragma unroll
    for (int c = 0; c < 64; ++c) {
        v[c] = src[c * HW];
        ss += v[c] * v[c];
    }
    float inv = 1.f / fmaxf(sqrtf(ss), 1e-12f);
    short* rd = reft + (size_t)p * 64;
#pragma unroll
    for (int cc = 0; cc < 8; ++cc) {
        bf16x8 o;
#pragma unroll
        for (int j = 0; j < 8; ++j) o[j] = f2bf(v[cc * 8 + j]);
        *(bf16x8*)(rd + cc * 8) = o;
    }
    float* nd = nrn + b * 64 * HW + ij;
#pragma unroll
    for (int c = 0; c < 64; ++c) nd[c * HW] = v[c] * inv;
}

// ---- pack conv weights (OIHW fp32) into MFMA-B fragment layout -------------
// dst[tap][kk][nt][lane][e]; ic = kk*32+(l>>4)*8+e, oc = nt*16+(l&15)
__global__ void k_prep(const float* __restrict__ src, short* __restrict__ dst,
                       int OC, int ICt, int ICsrc, int KH, int KW, int NT,
                       int fold, int total) {
    int i = blockIdx.x * 256 + threadIdx.x;
    if (i >= total) return;
    int e = i & 7, l = (i >> 3) & 63;
    int rest = i >> 9;
    int nt = rest % NT;
    rest /= NT;
    int ICK = ICt >> 5;
    int kk = rest % ICK;
    int tap = rest / ICK;
    int ic = kk * 32 + (l >> 4) * 8 + e;
    int oc = nt * 16 + (l & 15);
    int u = tap / KW, v = tap % KW;
    float val = 0.f;
    if (oc < OC) {
        val = src[((oc * ICsrc + ic) * KH + u) * KW + v];
        if (fold) val += src[((oc * ICsrc + 64 + ic) * KH + u) * KW + v];
    }
    dst[i] = f2bf(val);
}

// ---- channel-last bf16 implicit-GEMM conv ----------------------------------
// tile 8x32 px, 8 waves x (2 Mtiles x NTb Ntiles). X staged in LDS (XOR swz),
// B staged in LDS when BLDS, else streamed. NSPL: split OC across blocks.
// OMODE 0: bf16 ch-last + leaky; 1: bf16 ch-last 72 (no act); 2: NCHW fp32 + leaky
template <int KH, int KW, int IC, int OC, int OMODE, bool BLDS, int NSPL>
__global__ __launch_bounds__(512) void k_cmfma(
    const short* __restrict__ inA, const short* __restrict__ inB,
    const short* __restrict__ Bp, const float* __restrict__ bias,
    void* __restrict__ outp) {
    constexpr int TI = 8, TJ = 32;
    constexpr int PH = (KH - 1) / 2, PW = (KW - 1) / 2;
    constexpr int LR = TI + KH - 1, LC = TJ + KW - 1;
    constexpr int ICB = IC * 2;
    constexpr int LS = (ICB == 128) ? 7 : 8;
    constexpr int ICK = IC / 32;
    constexpr int NTF = (OC + 15) / 16;
    constexpr int NTb = NTF / NSPL;
    constexpr int TAPS = KH * KW;
    constexpr int NOCT = ICB / 16;
    __shared__ char Xs[LR * LC * ICB];
    __shared__ short Bs[BLDS ? TAPS * ICK * NTb * 512 : 8];
    const int tj0 = blockIdx.x * TJ, ti0 = blockIdx.y * TI;
    const int b = blockIdx.z / NSPL;
    const int nt0 = (blockIdx.z % NSPL) * NTb;
    const int tid = threadIdx.x;
    if (BLDS) {
        for (int u2 = tid; u2 < TAPS * ICK * NTb * 64; u2 += 512) {
            int l2 = u2 & 63;
            int rest = u2 >> 6;
            int nt = rest % NTb;
            int qk = rest / NTb;
            ((bf16x8*)Bs)[u2] = ((const bf16x8*)Bp)[(qk * NTF + nt0 + nt) * 64 + l2];
        }
    }
    for (int u2 = tid; u2 < LR * LC * NOCT; u2 += 512) {
        int oct = u2 % NOCT;
        int hp = u2 / NOCT;
        int hr = hp / LC, hc = hp % LC;
        int gi = ti0 + hr - PH, gj = tj0 + hc - PW;
        bf16x8 v = {};
        if (gi >= 0 && gi < H && gj >= 0 && gj < W) {
            const short* s = (oct < 8) ? inA : inB;
            v = *(const bf16x8*)(s + (size_t)(b * HW + gi * W + gj) * 64 +
                                 (oct & 7) * 8);
        }
        int byte = hp * ICB + oct * 16;
        byte ^= ((byte >> LS) & 7) << 4;
        *(bf16x8*)(Xs + byte) = v;
    }
    __syncthreads();
    const int wave = tid >> 6, l = tid & 63;
    const int r = l & 15, q = l >> 4;
    const int mt0 = wave * 2;
    int p0 = mt0 * 16 + r, p1 = p0 + 16;
    int li0 = p0 >> 5, lj0 = p0 & 31, li1 = p1 >> 5, lj1 = p1 & 31;
    f32x4 acc[2][NTb] = {};
#pragma unroll
    for (int t = 0; t < TAPS; ++t) {
        const int u = t / KW, v = t % KW;
        int hp0 = (li0 + u) * LC + (lj0 + v);
        int hp1 = (li1 + u) * LC + (lj1 + v);
#pragma unroll
        for (int kk = 0; kk < ICK; ++kk) {
            int ab0 = hp0 * ICB + kk * 64 + q * 16;
            ab0 ^= ((ab0 >> LS) & 7) << 4;
            int ab1 = hp1 * ICB + kk * 64 + q * 16;
            ab1 ^= ((ab1 >> LS) & 7) << 4;
            bf16x8 a0 = *(const bf16x8*)(Xs + ab0);
            bf16x8 a1 = *(const bf16x8*)(Xs + ab1);
            const short* bbase =
                BLDS ? (const short*)Bs + (t * ICK + kk) * NTb * 512 + l * 8
                     : Bp + ((t * ICK + kk) * NTF + nt0) * 512 + l * 8;
#pragma unroll
            for (int nt = 0; nt < NTb; ++nt) {
                bf16x8 bv = *(const bf16x8*)(bbase + nt * 512);
                acc[0][nt] =
                    __builtin_amdgcn_mfma_f32_16x16x32_bf16(a0, bv, acc[0][nt], 0, 0, 0);
                acc[1][nt] =
                    __builtin_amdgcn_mfma_f32_16x16x32_bf16(a1, bv, acc[1][nt], 0, 0, 0);
            }
        }
    }
    const int col = l & 15;
#pragma unroll
    for (int mt = 0; mt < 2; ++mt)
#pragma unroll
        for (int nt = 0; nt < NTb; ++nt) {
            int oc = (nt0 + nt) * 16 + col;
            float bs = (oc < OC) ? bias[oc] : 0.f;
#pragma unroll
            for (int j = 0; j < 4; ++j) {
                int p = (mt0 + mt) * 16 + q * 4 + j;
                int gi = ti0 + (p >> 5), gj = tj0 + (p & 31);
                float val = acc[mt][nt][j] + bs;
                if (OMODE == 0) {
                    val = leakyf(val);
                    *((short*)outp + (size_t)(b * HW + gi * W + gj) * 64 + oc) =
                        f2bf(val);
                } else if (OMODE == 1) {
                    if (oc < 72)
                        *((short*)outp + (size_t)(b * HW + gi * W + gj) * 72 + oc) =
                            f2bf(val);
                } else {
                    val = leakyf(val);
                    *((float*)outp + (size_t)(b * 64 + oc) * HW + gi * W + gj) = val;
                }
            }
        }
}

// ---- per-displacement dot map, NCHW, symmetry-halved -----------------------
// S[b][48-d][y+dy-3][x+dx-3] == S[b][d][y][x]; compute d<=24, mirror-write.
// Uncovered d>24 entries are structurally 0 (pre-zeroed by memset).
__global__ void k_corr_sym(const float* __restrict__ nr, float* __restrict__ S) {
    int idx = blockIdx.x * 256 + threadIdx.x;
    if (idx >= BATCH * 25 * 98 * 98) return;
    int x = idx % 98;
    int y = (idx / 98) % 98;
    int d = (idx / (98 * 98)) % 25;
    int b = idx / (98 * 98 * 25);
    int dy = d / 7, dx = d % 7;
    int f1i = y - 1, f1j = x - 1;
    int f2i = y + dy - 4, f2j = x + dx - 4;
    float r = 0.f;
    if (f1i >= 0 && f1i < H && f1j >= 0 && f1j < W && f2i >= 0 && f2i < H &&
        f2j >= 0 && f2j < W) {
        const float* p1 = nr + b * 64 * HW + f1i * W + f1j;
        const float* p2 = nr + b * 64 * HW + f2i * W + f2j;
#pragma unroll 16
        for (int c = 0; c < 64; ++c) r = fmaf(p1[c * HW], p2[c * HW], r);
    }
    S[((size_t)(b * 49 + d)) * (98 * 98) + y * 98 + x] = r;
    if (d < 24) {
        int y2 = y + dy - 3, x2 = x + dx - 3;
        if (y2 >= 0 && y2 < 98 && x2 >= 0 && x2 < 98)
            S[((size_t)(b * 49 + 48 - d)) * (98 * 98) + y2 * 98 + x2] = r;
    }
}

// ---- 3x3 window-sum per displacement + top-3 (stable: strict >) ------------
__global__ void k_topk(const float* __restrict__ S, int* __restrict__ idx3) {
    int p = blockIdx.x * 256 + threadIdx.x;
    if (p >= BATCH * HW) return;
    int b = p / HW, i = (p % HW) / W, j = p % W;
    float v0 = -1e30f, v1 = -1e30f, v2 = -1e30f;
    int d0 = 0, d1 = 0, d2 = 0;
    for (int d = 0; d < 49; ++d) {
        const float* s = S + ((b * 49 + d) * 98 + i) * 98 + j;
        float v = 0.f;
#pragma unroll
        for (int u = 0; u < 3; ++u)
#pragma unroll
            for (int vv = 0; vv < 3; ++vv) v += s[u * 98 + vv];
        if (v > v0) {
            v2 = v1; d2 = d1; v1 = v0; d1 = d0; v0 = v; d0 = d;
        } else if (v > v1) {
            v2 = v1; d2 = d1; v1 = v; d1 = d;
        } else if (v > v2) {
            v2 = v; d2 = d;
        }
    }
    idx3[p * 3 + 0] = d0;
    idx3[p * 3 + 1] = d1;
    idx3[p * 3 + 2] = d2;
}

// ---- pack wnn raw taps into MFMA-B fragments -------------------------------
// B2[nt(4)][n(3)][h2(2)][tap(9)][lane(64)][e(8)]; oc=nt*16+(l&15),
// c=h2*32+(l>>4)*8+e, weight = wnn[oc, n*64+c, u, v], tap=(u*3+v)
__global__ void k_bswz2(const float* __restrict__ wnn, short* __restrict__ B2) {
    int i = blockIdx.x * 256 + threadIdx.x;
    if (i >= 4 * 3 * 2 * 9 * 512) return;
    int e = i & 7, l = (i >> 3) & 63;
    int t = (i >> 9) % 9;
    int h2 = (i / (512 * 9)) % 2;
    int n = (i / (512 * 9 * 2)) % 3;
    int nt = i / (512 * 9 * 2 * 3);
    int oc = nt * 16 + (l & 15);
    int c = h2 * 32 + (l >> 4) * 8 + e;
    int u = t / 3, v = t % 3;
    B2[i] = f2bf(wnn[((oc * 192 + n * 64 + c) * 3 + u) * 3 + v]);
}

// ---- MFMA gather-conv + mask reduce, DMA-staged (global_load_lds) ----------
// A double-buffered per neighbor (2 x 36,864 B). LDS kept physically linear;
// the XOR bank-swizzle is realized by permuting lane->chunk on the DMA source
// (c = l ^ v, involutive with the read-side XOR). OOB taps read a zeroed pad.
__global__ __launch_bounds__(512, 4) void k_agg_mfma(
    const short* __restrict__ refT, const int* __restrict__ idx3,
    const short* __restrict__ B2, const float* __restrict__ bnn,
    const short* __restrict__ maskT, const short* __restrict__ zpad,
    short* __restrict__ agg) {
    constexpr int PX = 32;
    constexpr int BUFB = 36864;                   // bytes per buffer
    __shared__ short A_lds[2 * 2 * 18 * 64 * 8];  // 73,728 B
    __shared__ int sd[PX][NBR];
    const int p0 = blockIdx.x * PX;
    const int b = p0 / HW;
    const int i0 = (p0 % HW) / W;
    const int j0 = p0 % W;
    const int tid = threadIdx.x;
    const int wave = tid >> 6;
    const int lane = tid & 63;
    if (tid < PX * NBR)
        sd[tid / NBR][tid % NBR] = idx3[(p0 + tid / NBR) * NBR + tid % NBR];
    __syncthreads();

    // stage neighbor n into buffer buf: 36 regions of 1024 B, one wave-DMA each
    auto STAGE = [&](int n, int buf) {
        for (int r2 = wave; r2 < 36; r2 += 8) {
            int kkl = r2 % 18;
            int ph = r2 / 18;
            int rs = kkl >> 1;
            int oh = kkl & 1;
            int c = lane ^ (((lane >> 4) & 3) | (((buf * 36 + r2) & 1) << 2));
            int oct = oh * 4 + (c >> 4);
            int px = ph * 16 + (c & 15);
            int d = sd[px][n];
            int gi = i0 + d / 7 + rs / 3 - 4;
            int gj = j0 + px + d % 7 + rs % 3 - 4;
            const short* src = (gi >= 0 && gi < H && gj >= 0 && gj < W)
                                   ? refT + (size_t)(b * HW + gi * W + gj) * 64 +
                                         oct * 8
                                   : zpad;
            __builtin_amdgcn_global_load_lds(
                (const __attribute__((address_space(1))) void*)src,
                (__attribute__((address_space(3))) void*)((char*)A_lds +
                                                          buf * BUFB + r2 * 1024),
                16, 0, 0);
        }
    };

    const int w = wave & 3;      // oc slice
    const int half = wave >> 2;  // pixel group
    f32x4 acc[9] = {};
    const short* Bw = B2 + (size_t)w * (3 * 2 * 9 * 512) + lane * 8;

    auto COMPUTE = [&](int n, int buf) {
#pragma unroll
        for (int h2 = 0; h2 < 2; ++h2) {
            const short* bb = Bw + (n * 2 + h2) * 9 * 512;
            bf16x8 bv[9];
#pragma unroll
            for (int t = 0; t < 9; ++t) bv[t] = *(const bf16x8*)(bb + t * 512);
#pragma unroll
            for (int rs = 0; rs < 9; ++rs) {
                int kkl = rs * 2 + h2;
                int ab = buf * BUFB + ((((half * 18 + kkl) << 6) + lane) << 4);
                ab ^= ((ab >> 8) & 7) << 4;
                bf16x8 a = *(const bf16x8*)((char*)A_lds + ab);
#pragma unroll
                for (int t = 0; t < 9; ++t) {
                    const int y = rs / 3 - t / 3 + 1;
                    const int x = rs % 3 - t % 3 + 1;
                    if (y >= 0 && y < 3 && x >= 0 && x < 3)
                        acc[y * 3 + x] = __builtin_amdgcn_mfma_f32_16x16x32_bf16(
                            a, bv[t], acc[y * 3 + x], 0, 0, 0);
                }
            }
        }
    };

    STAGE(0, 0);
    STAGE(1, 1);
    __syncthreads();  // drain DMA: buf0+buf1 ready
    COMPUTE(0, 0);
    __syncthreads();  // all waves done reading buf0
    STAGE(2, 0);      // DMA flies under COMPUTE(1)
    COMPUTE(1, 1);
    __syncthreads();  // drain DMA: buf0 ready
    COMPUTE(2, 0);

    const int oc = w * 16 + (lane & 15);
    const float bn = bnn[oc];
    const int mrow = (lane >> 4) * 4;
#pragma unroll
    for (int j = 0; j < 4; ++j) {
        int px = half * 16 + mrow + j;
        int ij = i0 * W + j0 + px;
        const short* mb = maskT + (size_t)(b * HW + ij) * 72 + (oc >> 3) * 9;
        float sacc = 0.f;
#pragma unroll
        for (int yx = 0; yx < 9; ++yx) {
            float gv = leakyf(acc[yx][j] + bn);
            sacc += gv * bf2f(mb[yx]);
        }
        agg[(size_t)(b * HW + ij) * 64 + oc] = f2bf(leakyf(sacc));
    }
}

extern "C" void kernel_launch(void* const* d_in, const int* in_sizes, int n_in,
                              void* d_out, int out_size, void* d_ws,
                              size_t ws_size, hipStream_t stream) {
    const float* ref = (const float*)d_in[0];
    const float* w1 = (const float*)d_in[1];
    const float* b1 = (const float*)d_in[2];
    const float* w2 = (const float*)d_in[3];
    const float* b2 = (const float*)d_in[4];
    const float* w3 = (const float*)d_in[5];
    const float* b3 = (const float*)d_in[6];
    const float* w4 = (const float*)d_in[7];
    const float* b4 = (const float*)d_in[8];
    const float* wm = (const float*)d_in[9];
    const float* bm = (const float*)d_in[10];
    const float* wnn = (const float*)d_in[11];
    const float* bnn = (const float*)d_in[12];
    const float* wf = (const float*)d_in[13];
    const float* bf = (const float*)d_in[14];

    char* ws = (char*)d_ws;
    constexpr size_t O_NRN = 0;
    constexpr size_t O_S = O_NRN + (size_t)BATCH * HW * 64 * 4;
    constexpr size_t O_REFT = O_S + (size_t)BATCH * 49 * 98 * 98 * 4;
    constexpr size_t O_X1 = O_REFT + (size_t)BATCH * HW * 64 * 2;
    constexpr size_t O_X2 = O_X1 + (size_t)BATCH * HW * 64 * 2;
    constexpr size_t O_MASKT = O_X2 + (size_t)BATCH * HW * 64 * 2;
    constexpr size_t O_IDX = O_MASKT + (size_t)BATCH * HW * 72 * 2;
    constexpr size_t O_P1 = O_IDX + (size_t)BATCH * HW * 3 * 4;
    constexpr size_t O_P2 = O_P1 + 73728 * 2;
    constexpr size_t O_P3 = O_P2 + 73728 * 2;
    constexpr size_t O_P4 = O_P3 + 28672 * 2;
    constexpr size_t O_PM = O_P4 + 28672 * 2;
    constexpr size_t O_PF = O_PM + 46080 * 2;
    constexpr size_t O_ZP = O_PF + 73728 * 2;

    float* NRN = (float*)(ws + O_NRN);
    float* S = (float*)(ws + O_S);
    short* BSWZ2 = (short*)(ws + O_S);  // aliased: written after topk
    short* REFT = (short*)(ws + O_REFT);
    short* X1 = (short*)(ws + O_X1);
    short* X2 = (short*)(ws + O_X2);
    short* MASKT = (short*)(ws + O_MASKT);
    int* IDX = (int*)(ws + O_IDX);
    short* P1 = (short*)(ws + O_P1);
    short* P2 = (short*)(ws + O_P2);
    short* P3 = (short*)(ws + O_P3);
    short* P4 = (short*)(ws + O_P4);
    short* PM = (short*)(ws + O_PM);
    short* PF = (short*)(ws + O_PF);
    short* ZPAD = (short*)(ws + O_ZP);

    // input prep + weight packing
    k_pre<<<(BATCH * HW + 255) / 256, 256, 0, stream>>>(ref, REFT, NRN);
    k_prep<<<144, 256, 0, stream>>>(w1, P1, 64, 64, 128, 3, 3, 4, 1, 36864);
    k_prep<<<144, 256, 0, stream>>>(w2, P2, 64, 64, 64, 3, 3, 4, 0, 36864);
    k_prep<<<112, 256, 0, stream>>>(w3, P3, 64, 64, 64, 7, 1, 4, 0, 28672);
    k_prep<<<112, 256, 0, stream>>>(w4, P4, 64, 64, 64, 1, 7, 4, 0, 28672);
    k_prep<<<180, 256, 0, stream>>>(wm, PM, 72, 64, 64, 3, 3, 5, 0, 46080);
    k_prep<<<288, 256, 0, stream>>>(wf, PF, 64, 128, 128, 3, 3, 4, 0, 73728);

    dim3 cgrid2(3, 12, BATCH * 2);
    dim3 cgrid1(3, 12, BATCH);
    // mask branch (MFMA convs, bf16 channel-last chain, OC split x2)
    k_cmfma<3, 3, 64, 64, 0, true, 2><<<cgrid2, 512, 0, stream>>>(REFT, nullptr, P1, b1, X1);
    k_cmfma<3, 3, 64, 64, 0, true, 2><<<cgrid2, 512, 0, stream>>>(X1, nullptr, P2, b2, X2);
    k_cmfma<7, 1, 64, 64, 0, true, 2><<<cgrid2, 512, 0, stream>>>(X2, nullptr, P3, b3, X1);
    k_cmfma<1, 7, 64, 64, 0, true, 2><<<cgrid2, 512, 0, stream>>>(X1, nullptr, P4, b4, X2);
    k_cmfma<3, 3, 64, 72, 1, true, 1><<<cgrid1, 512, 0, stream>>>(X2, nullptr, PM, bm, MASKT);

    // correlation: zero-fill d>24 planes, compute d<=24 + mirror write
    for (int b = 0; b < BATCH; ++b)
        hipMemsetAsync(S + ((size_t)(b * 49 + 25)) * 98 * 98,
                       0, (size_t)24 * 98 * 98 * 4, stream);
    hipMemsetAsync(ZPAD, 0, 16, stream);
    k_corr_sym<<<(BATCH * 25 * 98 * 98 + 255) / 256, 256, 0, stream>>>(NRN, S);
    k_topk<<<BATCH * HW / 256, 256, 0, stream>>>(S, IDX);

    // raw-tap W2 pack (into dead S region)
    k_bswz2<<<432, 256, 0, stream>>>(wnn, BSWZ2);

    // MFMA gather-conv + mask-weighted aggregate -> X1 (bf16 ch-last)
    k_agg_mfma<<<BATCH * HW / 32, 512, 0, stream>>>(REFT, IDX, BSWZ2, bnn, MASKT,
                                                    ZPAD, X1);

    // final fusion conv: concat([ref, agg]) -> NCHW fp32 out
    k_cmfma<3, 3, 128, 64, 2, false, 1><<<cgrid1, 512, 0, stream>>>(REFT, X1, PF, bf, d_out);
}